// Round 23
// baseline (87.741 us; speedup 1.0000x reference)
//
#include <hip/hip_runtime.h>
#include <stdint.h>

#define BATCH 16
#define SEQ   4096
#define DIM   256
#define HW    64
#define NSTEP 10
#define DT    0.3f

typedef __attribute__((ext_vector_type(8))) short short8;   // 8 bf16 in 4 VGPRs
typedef __attribute__((ext_vector_type(4))) float f32x4;
typedef __attribute__((ext_vector_type(2))) float f32x2;

// ---------------------------------------------------------------------------
// Packed-f32 VOP3P helpers (throughput-neutral vs scalar per R8).
// ---------------------------------------------------------------------------
__device__ __forceinline__ f32x2 pk_add(f32x2 a, f32x2 b) {
  f32x2 d; asm("v_pk_add_f32 %0, %1, %2" : "=v"(d) : "v"(a), "v"(b)); return d;
}
__device__ __forceinline__ f32x2 pk_mul(f32x2 a, f32x2 b) {
  f32x2 d; asm("v_pk_mul_f32 %0, %1, %2" : "=v"(d) : "v"(a), "v"(b)); return d;
}
__device__ __forceinline__ f32x2 pk_fma_addk(f32x2 a, f32x2 b, f32x2 ks) {
  f32x2 d; asm("v_pk_fma_f32 %0, %1, %2, %3" : "=v"(d) : "v"(a), "v"(b), "s"(ks)); return d;
}
__device__ __forceinline__ f32x2 pk_fma_s1(f32x2 a, f32x2 ks, f32x2 c) {
  f32x2 d; asm("v_pk_fma_f32 %0, %1, %2, %3" : "=v"(d) : "v"(a), "s"(ks), "v"(c)); return d;
}

// DPP lane shifts (16-lane rows align with plane edges; bound_ctrl zeroes).
__device__ __forceinline__ float dpp_from_left(float x) {
  return __int_as_float(__builtin_amdgcn_update_dpp(
      0, __float_as_int(x), 0x111, 0xF, 0xF, true));
}
__device__ __forceinline__ float dpp_from_right(float x) {
  return __int_as_float(__builtin_amdgcn_update_dpp(
      0, __float_as_int(x), 0x101, 0xF, 0xF, true));
}

// ---------------------------------------------------------------------------
// W path: fp32 -> (bf16-hi, bf16-lo) split via TRUNCATE + v_perm (R17).
// ---------------------------------------------------------------------------
__device__ __forceinline__ void split_pack(float4 v, uint2& hi, uint2& lo) {
  uint32_t u0 = __float_as_uint(v.x), u1 = __float_as_uint(v.y);
  uint32_t u2 = __float_as_uint(v.z), u3 = __float_as_uint(v.w);
  float h0 = __uint_as_float(u0 & 0xFFFF0000u);
  float h1 = __uint_as_float(u1 & 0xFFFF0000u);
  float h2 = __uint_as_float(u2 & 0xFFFF0000u);
  float h3 = __uint_as_float(u3 & 0xFFFF0000u);
  hi.x = __builtin_amdgcn_perm(u1, u0, 0x07060302u);
  hi.y = __builtin_amdgcn_perm(u3, u2, 0x07060302u);
  lo.x = __builtin_amdgcn_perm(__float_as_uint(v.y - h1),
                               __float_as_uint(v.x - h0), 0x07060302u);
  lo.y = __builtin_amdgcn_perm(__float_as_uint(v.w - h3),
                               __float_as_uint(v.z - h2), 0x07060302u);
}

// X path: round-to-nearest-even bf16, HI ONLY (R21-verified).
__device__ __forceinline__ uint2 pack_hi_rne(float4 v) {
  uint32_t u0 = __float_as_uint(v.x); u0 += 0x7FFFu + ((u0 >> 16) & 1u);
  uint32_t u1 = __float_as_uint(v.y); u1 += 0x7FFFu + ((u1 >> 16) & 1u);
  uint32_t u2 = __float_as_uint(v.z); u2 += 0x7FFFu + ((u2 >> 16) & 1u);
  uint32_t u3 = __float_as_uint(v.w); u3 += 0x7FFFu + ((u3 >> 16) & 1u);
  uint2 hi;
  hi.x = __builtin_amdgcn_perm(u1, u0, 0x07060302u);
  hi.y = __builtin_amdgcn_perm(u3, u2, 0x07060302u);
  return hi;
}

// ---------------------------------------------------------------------------
// R23 prep: one-time W split -> Whi/Wlo bf16 tables (bitwise identical to the
// per-block split of R22, computed once instead of 512 times).
// ---------------------------------------------------------------------------
__global__ __launch_bounds__(256) void prep_w(
    const float* __restrict__ W, ushort* __restrict__ Whi,
    ushort* __restrict__ Wlo) {
  int idx = blockIdx.x * 256 + threadIdx.x;     // 16384 threads, 4 floats each
  float4 v = *(const float4*)(W + (size_t)idx * 4);
  uint2 hi, lo;
  split_pack(v, hi, lo);
  *(uint2*)(Whi + (size_t)idx * 4) = hi;
  *(uint2*)(Wlo + (size_t)idx * 4) = lo;
}

// ---------------------------------------------------------------------------
// GEMM: proj[(b*DIM+e)*SEQ + s] = bf16( sum_d x[b,s,d]*W[e,d] + bias[e] )
// bf16x2(W) x bf16(X) emulated-fp32 MFMA. R23: W staged from precomputed
// bf16 tables (plain 8-B copies, zero conversion math, -16 B/thread regs).
// ---------------------------------------------------------------------------
__global__ __launch_bounds__(256) void gemm_proj_mfma(
    const float* __restrict__ x, const ushort* __restrict__ Whi,
    const ushort* __restrict__ Wlo, const float* __restrict__ bias,
    ushort* __restrict__ proj) {
  const int eTile = blockIdx.x * 128;
  const int sTile = blockIdx.y * 128;
  const int b     = blockIdx.z;
  const int t     = threadIdx.x;
  const int lane  = t & 63;
  const int wid   = t >> 6;
  const int wr    = wid >> 1;
  const int wc    = wid & 1;

  __shared__ char lds[3 * 128 * 80];   // Whs, Wls, Xhs
  char* Whs = lds;
  char* Wls = lds + 10240;
  char* Xhs = lds + 20480;

  const float* xb = x + (size_t)b * SEQ * DIM;

  f32x4 acc[4][4] = {};
  uint2 regWh[4], regWl[4];
  float4 regX[4];

#define ISSUE_LOADS(KT)                                                        \
  {                                                                            \
    _Pragma("unroll")                                                          \
    for (int r = 0; r < 4; r++) {                                              \
      int ci = t + 256 * r;                                                    \
      int row = ci >> 3, q = ci & 7;                                           \
      size_t wof = (size_t)(eTile + row) * DIM + (KT) + q * 4;                 \
      regWh[r] = *(const uint2*)(Whi + wof);                                   \
      regWl[r] = *(const uint2*)(Wlo + wof);                                   \
      regX[r]  = *(const float4*)(xb + (size_t)(sTile + row) * DIM + (KT) + q * 4); \
    }                                                                          \
  }

  ISSUE_LOADS(0);

  for (int kt = 0; kt < DIM; kt += 32) {
    __syncthreads();
#pragma unroll
    for (int r = 0; r < 4; r++) {
      int ci = t + 256 * r;
      int row = ci >> 3, q = ci & 7;
      *(uint2*)(Whs + row * 80 + q * 8) = regWh[r];
      *(uint2*)(Wls + row * 80 + q * 8) = regWl[r];
      *(uint2*)(Xhs + row * 80 + q * 8) = pack_hi_rne(regX[r]);
    }
    __syncthreads();

    if (kt + 32 < DIM) ISSUE_LOADS(kt + 32);

    const int c16 = (lane >> 4) * 16;
    const int rlo = lane & 15;
    short8 bh[4];
#pragma unroll
    for (int j = 0; j < 4; j++) {
      int rowX = wc * 64 + j * 16 + rlo;
      bh[j] = *(const short8*)(Xhs + rowX * 80 + c16);
    }
#pragma unroll
    for (int i = 0; i < 4; i++) {
      int rowW = wr * 64 + i * 16 + rlo;
      short8 ah = *(const short8*)(Whs + rowW * 80 + c16);
      short8 al = *(const short8*)(Wls + rowW * 80 + c16);
#pragma unroll
      for (int j = 0; j < 4; j++) {
        acc[i][j] = __builtin_amdgcn_mfma_f32_16x16x32_bf16(ah, bh[j], acc[i][j], 0, 0, 0);
        acc[i][j] = __builtin_amdgcn_mfma_f32_16x16x32_bf16(al, bh[j], acc[i][j], 0, 0, 0);
      }
    }
  }
#undef ISSUE_LOADS

#pragma unroll
  for (int i = 0; i < 4; i++) {
    int e0 = eTile + wr * 64 + i * 16 + (lane >> 4) * 4;
#pragma unroll
    for (int reg = 0; reg < 4; reg++) {
      int e = e0 + reg;
      float bb = bias[e];
      ushort* orow = proj + ((size_t)(b * DIM + e)) * SEQ + sTile + wc * 64;
#pragma unroll
      for (int j = 0; j < 4; j++) {
        uint32_t uv = __float_as_uint(acc[i][j][reg] + bb);
        uv += 0x7FFFu + ((uv >> 16) & 1u);
        orow[j * 16 + (lane & 15)] = (ushort)(uv >> 16);
      }
    }
  }
}

// ---------------------------------------------------------------------------
// Evolve (unchanged from R22: 57.5 us, VGPR 24, FETCH 16.4 MB, 0 conflicts).
// LDS boundary-row table w/ zero sentinels; Pade[5/4]+Ac-fold tanh; shared
// rcp per 4 cells; DPP side halos; 1 barrier/step; bf16 proj input.
// ---------------------------------------------------------------------------
__global__ __launch_bounds__(256) void evolve_kernel(
    const ushort* __restrict__ proj, const float* __restrict__ dcoef,
    float* __restrict__ out) {
  const int tid   = threadIdx.x;
  const int w     = tid >> 6;
  const int lane  = tid & 63;
  const int plane = blockIdx.x;
  const int lx = lane & 15;
  const int ly = lane >> 4;

  __shared__ float bnd[2][34][64];   // 17408 B
  __shared__ float psum[4];

  const float D   = dcoef[0];
  const float DDf = DT * D;
  const float Acf = 1.f - DT - 4.f * DDf;
  const float DDu = __uint_as_float(__builtin_amdgcn_readfirstlane(__float_as_uint(DDf)));
  const float Acu = __uint_as_float(__builtin_amdgcn_readfirstlane(__float_as_uint(Acf)));
  const float PAf = DT + 6.f * Acu;
  const float P0f = 15.f * (DT + Acu);
  const float P0u = __uint_as_float(__builtin_amdgcn_readfirstlane(__float_as_uint(P0f)));
  const f32x2 kDD  = {DDu, DDu};
  const f32x2 kP0  = {P0u, P0u};
  const f32x2 k15  = {15.f, 15.f};
  const f32x2 kPAv = {PAf, PAf};
  const f32x2 k6v  = {6.f, 6.f};

  const ushort* p = proj + (size_t)plane * (HW * HW)
                  + (size_t)(w * 16 + ly * 4) * HW + lx * 4;

  f32x2 u[4][2];
#pragma unroll
  for (int r = 0; r < 4; r++) {
    ushort4 v = *(const ushort4*)(p + r * HW);
    u[r][0].x = __uint_as_float((uint32_t)v.x << 16);
    u[r][0].y = __uint_as_float((uint32_t)v.y << 16);
    u[r][1].x = __uint_as_float((uint32_t)v.z << 16);
    u[r][1].y = __uint_as_float((uint32_t)v.w << 16);
  }

  auto pair2 = [&](f32x2 svA, f32x2 svB, f32x2 s4A, f32x2 s4B,
                   f32x2& zA, f32x2& zB) {
    f32x2 yA = pk_mul(svA, svA), yB = pk_mul(svB, svB);
    f32x2 tA = pk_fma_addk(yA, kPAv, kP0);
    f32x2 tB = pk_fma_addk(yB, kPAv, kP0);
    f32x2 nA = pk_mul(svA, tA);
    f32x2 nB = pk_mul(svB, tB);
    f32x2 dA = pk_fma_addk(yA, k6v, k15);
    f32x2 dB = pk_fma_addk(yB, k6v, k15);
    float pA = dA.x * dA.y, qB = dB.x * dB.y;
    float rr = __builtin_amdgcn_rcpf(pA * qB);
    float qr = qB * rr, pr = pA * rr;
    f32x2 iA; iA.x = dA.y * qr; iA.y = dA.x * qr;
    f32x2 iB; iB.x = dB.y * pr; iB.y = dB.x * pr;
    zA = pk_fma_s1(s4A, kDD, pk_mul(nA, iA));
    zB = pk_fma_s1(s4B, kDD, pk_mul(nB, iB));
  };

  const int base = w * 8 + ly * 2;

  {
    int bsel = tid >> 7;
    int ssel = (tid >> 6) & 1;
    bnd[bsel][ssel * 33][lane] = 0.f;
  }
  {
    float4 pub0; pub0.x = u[0][0].x; pub0.y = u[0][0].y;
    pub0.z = u[0][1].x; pub0.w = u[0][1].y;
    *(float4*)&bnd[0][base + 1][lx * 4] = pub0;
    float4 pub3; pub3.x = u[3][0].x; pub3.y = u[3][0].y;
    pub3.z = u[3][1].x; pub3.w = u[3][1].y;
    *(float4*)&bnd[0][base + 2][lx * 4] = pub3;
  }
  __syncthreads();

#pragma unroll 1
  for (int step = 0; step < NSTEP; step++) {
    const int rb = step & 1, wb = rb ^ 1;
    float4 thv = *(const float4*)&bnd[rb][base][lx * 4];
    float4 bhv = *(const float4*)&bnd[rb][base + 3][lx * 4];
    f32x2 th0 = {thv.x, thv.y}, th1 = {thv.z, thv.w};
    f32x2 bh0 = {bhv.x, bhv.y}, bh1 = {bhv.z, bhv.w};

    f32x2 prev0 = th0, prev1 = th1;
#pragma unroll
    for (int r = 0; r < 4; r++) {
      f32x2 sv0 = u[r][0], sv1 = u[r][1];
      float lfv = dpp_from_left(sv1.y);
      float rtv = dpp_from_right(sv0.x);
      f32x2 dn0 = (r < 3) ? u[r + 1][0] : bh0;
      f32x2 dn1 = (r < 3) ? u[r + 1][1] : bh1;
      f32x2 hs0, hs1;
      hs0.x = lfv + sv0.y;   hs0.y = sv0.x + sv1.x;
      hs1.x = sv0.y + sv1.y; hs1.y = sv1.x + rtv;
      f32x2 s40 = pk_add(pk_add(prev0, dn0), hs0);
      f32x2 s41 = pk_add(pk_add(prev1, dn1), hs1);
      pair2(sv0, sv1, s40, s41, u[r][0], u[r][1]);
      prev0 = sv0; prev1 = sv1;
    }

    float4 pub0; pub0.x = u[0][0].x; pub0.y = u[0][0].y;
    pub0.z = u[0][1].x; pub0.w = u[0][1].y;
    *(float4*)&bnd[wb][base + 1][lx * 4] = pub0;
    float4 pub3; pub3.x = u[3][0].x; pub3.y = u[3][0].y;
    pub3.z = u[3][1].x; pub3.w = u[3][1].y;
    *(float4*)&bnd[wb][base + 2][lx * 4] = pub3;
    __syncthreads();
  }

  float s = 0.f;
#pragma unroll
  for (int r = 0; r < 4; r++)
#pragma unroll
    for (int q = 0; q < 2; q++) s += u[r][q].x + u[r][q].y;
#pragma unroll
  for (int off = 32; off > 0; off >>= 1) s += __shfl_xor(s, off);
  if (lane == 0) psum[w] = s;
  __syncthreads();
  if (w == 0 && lane == 0)
    out[plane] = (psum[0] + psum[1] + psum[2] + psum[3]) * (1.f / (HW * HW));
}

// ---------------------------------------------------------------------------
extern "C" void kernel_launch(void* const* d_in, const int* in_sizes, int n_in,
                              void* d_out, int out_size, void* d_ws, size_t ws_size,
                              hipStream_t stream) {
  const float* x    = (const float*)d_in[0];
  const float* W    = (const float*)d_in[1];
  const float* bias = (const float*)d_in[2];
  const float* dc   = (const float*)d_in[3];
  float* out   = (float*)d_out;
  // workspace layout: proj bf16 (32 MB) | Whi (128 KB) | Wlo (128 KB)
  ushort* proj = (ushort*)d_ws;
  ushort* Whi  = (ushort*)((char*)d_ws + (size_t)BATCH * DIM * SEQ * 2);
  ushort* Wlo  = Whi + DIM * DIM;

  prep_w<<<DIM * DIM / (256 * 4), 256, 0, stream>>>(W, Whi, Wlo);

  dim3 g1(DIM / 128, SEQ / 128, BATCH);
  gemm_proj_mfma<<<g1, 256, 0, stream>>>(x, Whi, Wlo, bias, proj);

  evolve_kernel<<<BATCH * DIM, 256, 0, stream>>>(proj, dc, out);
}

// Round 24
// 83.020 us; speedup vs baseline: 1.0569x; 1.0569x over previous
//
#include <hip/hip_runtime.h>
#include <stdint.h>

#define BATCH 16
#define SEQ   4096
#define DIM   256
#define HW    64
#define NSTEP 10
#define DT    0.3f

typedef __attribute__((ext_vector_type(8))) short short8;   // 8 bf16 in 4 VGPRs
typedef __attribute__((ext_vector_type(4))) float f32x4;
typedef __attribute__((ext_vector_type(2))) float f32x2;

// ---------------------------------------------------------------------------
// Packed-f32 VOP3P helpers (throughput-neutral vs scalar per R8).
// ---------------------------------------------------------------------------
__device__ __forceinline__ f32x2 pk_add(f32x2 a, f32x2 b) {
  f32x2 d; asm("v_pk_add_f32 %0, %1, %2" : "=v"(d) : "v"(a), "v"(b)); return d;
}
__device__ __forceinline__ f32x2 pk_mul(f32x2 a, f32x2 b) {
  f32x2 d; asm("v_pk_mul_f32 %0, %1, %2" : "=v"(d) : "v"(a), "v"(b)); return d;
}
__device__ __forceinline__ f32x2 pk_fma_addk(f32x2 a, f32x2 b, f32x2 ks) {
  f32x2 d; asm("v_pk_fma_f32 %0, %1, %2, %3" : "=v"(d) : "v"(a), "v"(b), "s"(ks)); return d;
}
__device__ __forceinline__ f32x2 pk_fma_s1(f32x2 a, f32x2 ks, f32x2 c) {
  f32x2 d; asm("v_pk_fma_f32 %0, %1, %2, %3" : "=v"(d) : "v"(a), "s"(ks), "v"(c)); return d;
}

// DPP lane shifts (16-lane rows align with plane edges; bound_ctrl zeroes).
__device__ __forceinline__ float dpp_from_left(float x) {
  return __int_as_float(__builtin_amdgcn_update_dpp(
      0, __float_as_int(x), 0x111, 0xF, 0xF, true));
}
__device__ __forceinline__ float dpp_from_right(float x) {
  return __int_as_float(__builtin_amdgcn_update_dpp(
      0, __float_as_int(x), 0x101, 0xF, 0xF, true));
}

// ---------------------------------------------------------------------------
// W path: fp32 -> (bf16-hi, bf16-lo) split via TRUNCATE + v_perm (R17).
// R23 lesson: hoisting this into a prep kernel costs an extra launch (~5 us)
// that outweighs the staging VALU saved — keep the split in-block.
// ---------------------------------------------------------------------------
__device__ __forceinline__ void split_pack(float4 v, uint2& hi, uint2& lo) {
  uint32_t u0 = __float_as_uint(v.x), u1 = __float_as_uint(v.y);
  uint32_t u2 = __float_as_uint(v.z), u3 = __float_as_uint(v.w);
  float h0 = __uint_as_float(u0 & 0xFFFF0000u);
  float h1 = __uint_as_float(u1 & 0xFFFF0000u);
  float h2 = __uint_as_float(u2 & 0xFFFF0000u);
  float h3 = __uint_as_float(u3 & 0xFFFF0000u);
  hi.x = __builtin_amdgcn_perm(u1, u0, 0x07060302u);
  hi.y = __builtin_amdgcn_perm(u3, u2, 0x07060302u);
  lo.x = __builtin_amdgcn_perm(__float_as_uint(v.y - h1),
                               __float_as_uint(v.x - h0), 0x07060302u);
  lo.y = __builtin_amdgcn_perm(__float_as_uint(v.w - h3),
                               __float_as_uint(v.z - h2), 0x07060302u);
}

// X path: round-to-nearest-even bf16, HI ONLY (R21, verified: absmax
// unchanged — dropped x-lo term is noise-level after spatial mean).
__device__ __forceinline__ uint2 pack_hi_rne(float4 v) {
  uint32_t u0 = __float_as_uint(v.x); u0 += 0x7FFFu + ((u0 >> 16) & 1u);
  uint32_t u1 = __float_as_uint(v.y); u1 += 0x7FFFu + ((u1 >> 16) & 1u);
  uint32_t u2 = __float_as_uint(v.z); u2 += 0x7FFFu + ((u2 >> 16) & 1u);
  uint32_t u3 = __float_as_uint(v.w); u3 += 0x7FFFu + ((u3 >> 16) & 1u);
  uint2 hi;
  hi.x = __builtin_amdgcn_perm(u1, u0, 0x07060302u);
  hi.y = __builtin_amdgcn_perm(u3, u2, 0x07060302u);
  return hi;
}

// ---------------------------------------------------------------------------
// GEMM: proj[(b*DIM+e)*SEQ + s] = bf16( sum_d x[b,s,d]*W[e,d] + bias[e] )
// bf16x2(W) x bf16(X) emulated-fp32 MFMA. proj stored as bf16 RNE (R22) —
// halves the intermediate's write (gemm) and read (evolve) HBM traffic.
// IC quantization ~1e-3/cell, independent -> ~1.6e-5 after the 4096-cell
// spatial mean; negligible vs Pade's 2.44e-4 (threshold 7.57e-4).
// ---------------------------------------------------------------------------
__global__ __launch_bounds__(256) void gemm_proj_mfma(
    const float* __restrict__ x, const float* __restrict__ W,
    const float* __restrict__ bias, ushort* __restrict__ proj) {
  const int eTile = blockIdx.x * 128;
  const int sTile = blockIdx.y * 128;
  const int b     = blockIdx.z;
  const int t     = threadIdx.x;
  const int lane  = t & 63;
  const int wid   = t >> 6;
  const int wr    = wid >> 1;
  const int wc    = wid & 1;

  __shared__ char lds[3 * 128 * 80];   // Whs, Wls, Xhs
  char* Whs = lds;
  char* Wls = lds + 10240;
  char* Xhs = lds + 20480;

  const float* xb = x + (size_t)b * SEQ * DIM;

  f32x4 acc[4][4] = {};
  float4 regW[4], regX[4];

#define ISSUE_LOADS(KT)                                                        \
  {                                                                            \
    _Pragma("unroll")                                                          \
    for (int r = 0; r < 4; r++) {                                              \
      int ci = t + 256 * r;                                                    \
      int row = ci >> 3, q = ci & 7;                                           \
      regW[r] = *(const float4*)(W  + (size_t)(eTile + row) * DIM + (KT) + q * 4); \
      regX[r] = *(const float4*)(xb + (size_t)(sTile + row) * DIM + (KT) + q * 4); \
    }                                                                          \
  }

  ISSUE_LOADS(0);

  for (int kt = 0; kt < DIM; kt += 32) {
    __syncthreads();
#pragma unroll
    for (int r = 0; r < 4; r++) {
      int ci = t + 256 * r;
      int row = ci >> 3, q = ci & 7;
      uint2 hi, lo;
      split_pack(regW[r], hi, lo);
      *(uint2*)(Whs + row * 80 + q * 8) = hi;
      *(uint2*)(Wls + row * 80 + q * 8) = lo;
      *(uint2*)(Xhs + row * 80 + q * 8) = pack_hi_rne(regX[r]);
    }
    __syncthreads();

    if (kt + 32 < DIM) ISSUE_LOADS(kt + 32);

    const int c16 = (lane >> 4) * 16;
    const int rlo = lane & 15;
    short8 bh[4];
#pragma unroll
    for (int j = 0; j < 4; j++) {
      int rowX = wc * 64 + j * 16 + rlo;
      bh[j] = *(const short8*)(Xhs + rowX * 80 + c16);
    }
#pragma unroll
    for (int i = 0; i < 4; i++) {
      int rowW = wr * 64 + i * 16 + rlo;
      short8 ah = *(const short8*)(Whs + rowW * 80 + c16);
      short8 al = *(const short8*)(Wls + rowW * 80 + c16);
#pragma unroll
      for (int j = 0; j < 4; j++) {
        acc[i][j] = __builtin_amdgcn_mfma_f32_16x16x32_bf16(ah, bh[j], acc[i][j], 0, 0, 0);
        acc[i][j] = __builtin_amdgcn_mfma_f32_16x16x32_bf16(al, bh[j], acc[i][j], 0, 0, 0);
      }
    }
  }
#undef ISSUE_LOADS

#pragma unroll
  for (int i = 0; i < 4; i++) {
    int e0 = eTile + wr * 64 + i * 16 + (lane >> 4) * 4;
#pragma unroll
    for (int reg = 0; reg < 4; reg++) {
      int e = e0 + reg;
      float bb = bias[e];
      ushort* orow = proj + ((size_t)(b * DIM + e)) * SEQ + sTile + wc * 64;
#pragma unroll
      for (int j = 0; j < 4; j++) {
        uint32_t uv = __float_as_uint(acc[i][j][reg] + bb);
        uv += 0x7FFFu + ((uv >> 16) & 1u);
        orow[j * 16 + (lane & 15)] = (ushort)(uv >> 16);
      }
    }
  }
}

// ---------------------------------------------------------------------------
// Evolve (R20 structure; reads bf16 proj). All vertical halos via the
// double-buffered LDS boundary-row table with zero sentinels (zero shfls /
// selects / divergent publishes). Pade[5/4]+Ac-fold tanh, shared rcp per
// 4 cells, DPP side halos. 1 barrier/step. VGPR 24, zero bank conflicts.
// ---------------------------------------------------------------------------
__global__ __launch_bounds__(256) void evolve_kernel(
    const ushort* __restrict__ proj, const float* __restrict__ dcoef,
    float* __restrict__ out) {
  const int tid   = threadIdx.x;
  const int w     = tid >> 6;
  const int lane  = tid & 63;
  const int plane = blockIdx.x;
  const int lx = lane & 15;
  const int ly = lane >> 4;

  __shared__ float bnd[2][34][64];   // 17408 B
  __shared__ float psum[4];

  const float D   = dcoef[0];
  const float DDf = DT * D;
  const float Acf = 1.f - DT - 4.f * DDf;
  const float DDu = __uint_as_float(__builtin_amdgcn_readfirstlane(__float_as_uint(DDf)));
  const float Acu = __uint_as_float(__builtin_amdgcn_readfirstlane(__float_as_uint(Acf)));
  const float PAf = DT + 6.f * Acu;
  const float P0f = 15.f * (DT + Acu);
  const float P0u = __uint_as_float(__builtin_amdgcn_readfirstlane(__float_as_uint(P0f)));
  const f32x2 kDD  = {DDu, DDu};
  const f32x2 kP0  = {P0u, P0u};
  const f32x2 k15  = {15.f, 15.f};
  const f32x2 kPAv = {PAf, PAf};
  const f32x2 k6v  = {6.f, 6.f};

  const ushort* p = proj + (size_t)plane * (HW * HW)
                  + (size_t)(w * 16 + ly * 4) * HW + lx * 4;

  f32x2 u[4][2];
#pragma unroll
  for (int r = 0; r < 4; r++) {
    ushort4 v = *(const ushort4*)(p + r * HW);
    u[r][0].x = __uint_as_float((uint32_t)v.x << 16);
    u[r][0].y = __uint_as_float((uint32_t)v.y << 16);
    u[r][1].x = __uint_as_float((uint32_t)v.z << 16);
    u[r][1].y = __uint_as_float((uint32_t)v.w << 16);
  }

  auto pair2 = [&](f32x2 svA, f32x2 svB, f32x2 s4A, f32x2 s4B,
                   f32x2& zA, f32x2& zB) {
    f32x2 yA = pk_mul(svA, svA), yB = pk_mul(svB, svB);
    f32x2 tA = pk_fma_addk(yA, kPAv, kP0);
    f32x2 tB = pk_fma_addk(yB, kPAv, kP0);
    f32x2 nA = pk_mul(svA, tA);
    f32x2 nB = pk_mul(svB, tB);
    f32x2 dA = pk_fma_addk(yA, k6v, k15);
    f32x2 dB = pk_fma_addk(yB, k6v, k15);
    float pA = dA.x * dA.y, qB = dB.x * dB.y;
    float rr = __builtin_amdgcn_rcpf(pA * qB);
    float qr = qB * rr, pr = pA * rr;
    f32x2 iA; iA.x = dA.y * qr; iA.y = dA.x * qr;
    f32x2 iB; iB.x = dB.y * pr; iB.y = dB.x * pr;
    zA = pk_fma_s1(s4A, kDD, pk_mul(nA, iA));
    zB = pk_fma_s1(s4B, kDD, pk_mul(nB, iB));
  };

  const int base = w * 8 + ly * 2;

  // prologue: zero sentinels (slots 0 & 33, both buffers) + publish OLD rows
  {
    int bsel = tid >> 7;
    int ssel = (tid >> 6) & 1;
    bnd[bsel][ssel * 33][lane] = 0.f;
  }
  {
    float4 pub0; pub0.x = u[0][0].x; pub0.y = u[0][0].y;
    pub0.z = u[0][1].x; pub0.w = u[0][1].y;
    *(float4*)&bnd[0][base + 1][lx * 4] = pub0;
    float4 pub3; pub3.x = u[3][0].x; pub3.y = u[3][0].y;
    pub3.z = u[3][1].x; pub3.w = u[3][1].y;
    *(float4*)&bnd[0][base + 2][lx * 4] = pub3;
  }
  __syncthreads();

#pragma unroll 1
  for (int step = 0; step < NSTEP; step++) {
    const int rb = step & 1, wb = rb ^ 1;
    float4 thv = *(const float4*)&bnd[rb][base][lx * 4];
    float4 bhv = *(const float4*)&bnd[rb][base + 3][lx * 4];
    f32x2 th0 = {thv.x, thv.y}, th1 = {thv.z, thv.w};
    f32x2 bh0 = {bhv.x, bhv.y}, bh1 = {bhv.z, bhv.w};

    f32x2 prev0 = th0, prev1 = th1;
#pragma unroll
    for (int r = 0; r < 4; r++) {
      f32x2 sv0 = u[r][0], sv1 = u[r][1];
      float lfv = dpp_from_left(sv1.y);
      float rtv = dpp_from_right(sv0.x);
      f32x2 dn0 = (r < 3) ? u[r + 1][0] : bh0;
      f32x2 dn1 = (r < 3) ? u[r + 1][1] : bh1;
      f32x2 hs0, hs1;
      hs0.x = lfv + sv0.y;   hs0.y = sv0.x + sv1.x;
      hs1.x = sv0.y + sv1.y; hs1.y = sv1.x + rtv;
      f32x2 s40 = pk_add(pk_add(prev0, dn0), hs0);
      f32x2 s41 = pk_add(pk_add(prev1, dn1), hs1);
      pair2(sv0, sv1, s40, s41, u[r][0], u[r][1]);
      prev0 = sv0; prev1 = sv1;
    }

    float4 pub0; pub0.x = u[0][0].x; pub0.y = u[0][0].y;
    pub0.z = u[0][1].x; pub0.w = u[0][1].y;
    *(float4*)&bnd[wb][base + 1][lx * 4] = pub0;
    float4 pub3; pub3.x = u[3][0].x; pub3.y = u[3][0].y;
    pub3.z = u[3][1].x; pub3.w = u[3][1].y;
    *(float4*)&bnd[wb][base + 2][lx * 4] = pub3;
    __syncthreads();
  }

  float s = 0.f;
#pragma unroll
  for (int r = 0; r < 4; r++)
#pragma unroll
    for (int q = 0; q < 2; q++) s += u[r][q].x + u[r][q].y;
#pragma unroll
  for (int off = 32; off > 0; off >>= 1) s += __shfl_xor(s, off);
  if (lane == 0) psum[w] = s;
  __syncthreads();
  if (w == 0 && lane == 0)
    out[plane] = (psum[0] + psum[1] + psum[2] + psum[3]) * (1.f / (HW * HW));
}

// ---------------------------------------------------------------------------
extern "C" void kernel_launch(void* const* d_in, const int* in_sizes, int n_in,
                              void* d_out, int out_size, void* d_ws, size_t ws_size,
                              hipStream_t stream) {
  const float* x    = (const float*)d_in[0];
  const float* W    = (const float*)d_in[1];
  const float* bias = (const float*)d_in[2];
  const float* dc   = (const float*)d_in[3];
  float* out   = (float*)d_out;
  ushort* proj = (ushort*)d_ws;   // BATCH*DIM*SEQ*2 = 32 MB (bf16)

  dim3 g1(DIM / 128, SEQ / 128, BATCH);
  gemm_proj_mfma<<<g1, 256, 0, stream>>>(x, W, bias, proj);

  evolve_kernel<<<BATCH * DIM, 256, 0, stream>>>(proj, dc, out);
}